// Round 5
// baseline (443.868 us; speedup 1.0000x reference)
//
#include <hip/hip_runtime.h>
#include <hip/hip_bf16.h>

// Problem constants (from reference setup_inputs)
constexpr int B_   = 8;       // batch
constexpr int A_   = 120000;  // anchors
constexpr int C_   = 80;      // classes
constexpr int M_   = 32;      // max annotations per image
constexpr int APB  = 256;     // anchors per block
constexpr int C4   = C_ / 4;  // float4s per anchor row of classifications
constexpr int GX   = (A_ + APB - 1) / APB;   // 469 blocks per image

#define F_LN2 0.69314718056f
#define C0_ (0.75f * F_LN2)   // (1-alpha)*ln2  (negatives / non-target classes)
#define C1_ (0.25f * F_LN2)   // alpha*ln2      (target class on positives)

// ws layout (floats):
//   mask  [B*A]          (written unconditionally per anchor -> no memset)
//   PA_reg[B*GX]  PA_np[B*GX]  PA_cor[B*GX]  PB_cls[B*GX]
constexpr size_t WS_MASK   = 0;
constexpr size_t WS_PA_REG = (size_t)B_ * A_;
constexpr size_t WS_PA_NP  = WS_PA_REG + (size_t)B_ * GX;
constexpr size_t WS_PA_COR = WS_PA_NP  + (size_t)B_ * GX;
constexpr size_t WS_PB_CLS = WS_PA_COR + (size_t)B_ * GX;

__device__ __forceinline__ float smooth_l1(float d) {
    return (d <= (1.0f / 9.0f)) ? 4.5f * d * d : d - (0.5f / 9.0f);
}

__device__ __forceinline__ float clampp(float x) {
    return fminf(fmaxf(x, 1e-4f), 1.0f - 1e-4f);
}

// focal term for target==0: (1-alpha) * p^2 * (-ln(1-p))
__device__ __forceinline__ float f_neg(float p) {
    return C0_ * p * p * (-__log2f(1.0f - p));
}
// focal term for target==1: alpha * (1-p)^2 * (-ln p)
__device__ __forceinline__ float f_pos(float p) {
    const float q = 1.0f - p;
    return C1_ * q * q * (-__log2f(p));
}

// ---------------- Kernel A: anchor assignment (VALU-only, no streaming) ------
__global__ __launch_bounds__(256) void assign_k(
    const float* __restrict__ cls,   // [B,A,C] (scattered gather for positives)
    const float* __restrict__ reg,   // [B,A,4]
    const float* __restrict__ anc,   // [A,4]
    const float* __restrict__ ann,   // [B,M,5]
    float* __restrict__ mask,        // [B*A] out: 0=ignore band, 1 otherwise
    float* __restrict__ PA_reg,      // [B*GX]
    float* __restrict__ PA_np,       // [B*GX]
    float* __restrict__ PA_cor)      // [B*GX] cls correction for positives
{
    __shared__ float s_ann[M_ * 5];
    __shared__ float s_red[3][4];

    const int b   = blockIdx.y;
    const int a0  = blockIdx.x * APB;
    const int tid = threadIdx.x;
    const int na  = min(APB, A_ - a0);

    if (tid < M_ * 5) s_ann[tid] = ann[b * M_ * 5 + tid];
    __syncthreads();

    float rsum = 0.0f, npos = 0.0f, corr = 0.0f;

    if (tid < na) {
        const int a = a0 + tid;
        const float4 ab = reinterpret_cast<const float4*>(anc)[a];
        const float ax1 = ab.x, ay1 = ab.y, ax2 = ab.z, ay2 = ab.w;
        const float area_a = (ax2 - ax1) * (ay2 - ay1);

        float best = -2.0f;
        int   arg  = 0;
        #pragma unroll
        for (int m = 0; m < M_; ++m) {
            const float bx1 = s_ann[m * 5 + 0];
            const float by1 = s_ann[m * 5 + 1];
            const float bx2 = s_ann[m * 5 + 2];
            const float by2 = s_ann[m * 5 + 3];
            const float lab = s_ann[m * 5 + 4];
            const float iw = fmaxf(fminf(ax2, bx2) - fmaxf(ax1, bx1), 0.0f);
            const float ih = fmaxf(fminf(ay2, by2) - fmaxf(ay1, by1), 0.0f);
            const float inter  = iw * ih;
            const float area_b = (bx2 - bx1) * (by2 - by1);
            const float ua = fmaxf(area_a + area_b - inter, 1e-8f);
            float iou = inter * __builtin_amdgcn_rcpf(ua);   // ~1ulp, flips only knife-edge anchors
            if (lab == -1.0f) iou = -1.0f;                   // invalid GT never matched
            if (iou > best) { best = iou; arg = m; }         // first-occurrence argmax
        }

        float mk = 1.0f;
        if (best >= 0.5f) {
            const int code = (int)s_ann[arg * 5 + 4];
            const float gx1 = s_ann[arg * 5 + 0];
            const float gy1 = s_ann[arg * 5 + 1];
            const float gx2 = s_ann[arg * 5 + 2];
            const float gy2 = s_ann[arg * 5 + 3];
            float gw = gx2 - gx1, gh = gy2 - gy1;
            const float gcx = gx1 + 0.5f * gw;
            const float gcy = gy1 + 0.5f * gh;
            gw = fmaxf(gw, 1.0f);
            gh = fmaxf(gh, 1.0f);
            const float aw  = ax2 - ax1, ah = ay2 - ay1;
            const float acx = ax1 + 0.5f * aw;
            const float acy = ay1 + 0.5f * ah;
            const float t0 = ((gcx - acx) / aw) * 10.0f;
            const float t1 = ((gcy - acy) / ah) * 10.0f;
            const float t2 = __log2f(gw / aw) * (5.0f * F_LN2);
            const float t3 = __log2f(gh / ah) * (5.0f * F_LN2);
            const float4 rp = reinterpret_cast<const float4*>(reg)[(size_t)b * A_ + a];
            rsum = smooth_l1(fabsf(t0 - rp.x))
                 + smooth_l1(fabsf(t1 - rp.y))
                 + smooth_l1(fabsf(t2 - rp.z))
                 + smooth_l1(fabsf(t3 - rp.w));
            npos = 1.0f;
            const float p = clampp(cls[((size_t)b * A_ + a) * C_ + code]);
            corr = f_pos(p) - f_neg(p);   // stream kernel adds f_neg for every class
        } else if (best >= 0.4f) {
            mk = 0.0f;                    // ignore band: whole row contributes 0
        }
        mask[(size_t)b * A_ + a] = mk;
    }

    #pragma unroll
    for (int off = 32; off > 0; off >>= 1) {
        rsum += __shfl_down(rsum, off, 64);
        npos += __shfl_down(npos, off, 64);
        corr += __shfl_down(corr, off, 64);
    }
    const int wv = tid >> 6;
    if ((tid & 63) == 0) { s_red[0][wv] = rsum; s_red[1][wv] = npos; s_red[2][wv] = corr; }
    __syncthreads();
    if (tid == 0) {
        const int slot = b * GX + blockIdx.x;
        PA_reg[slot] = s_red[0][0] + s_red[0][1] + s_red[0][2] + s_red[0][3];
        PA_np [slot] = s_red[1][0] + s_red[1][1] + s_red[1][2] + s_red[1][3];
        PA_cor[slot] = s_red[2][0] + s_red[2][1] + s_red[2][2] + s_red[2][3];
    }
}

// ---------------- Kernel B: pure streaming focal reduce ----------------------
__global__ __launch_bounds__(256) void stream_k(
    const float* __restrict__ cls,   // [B,A,C]
    const float* __restrict__ mask,  // [B*A]
    float* __restrict__ PB_cls)      // [B*GX]
{
    __shared__ float s_red[4];

    const int b   = blockIdx.y;
    const int a0  = blockIdx.x * APB;
    const int tid = threadIdx.x;
    const int na  = min(APB, A_ - a0);
    const int total = na * C4;

    const float4* cp = reinterpret_cast<const float4*>(cls) + ((size_t)b * A_ + a0) * C4;
    const float*  mb = mask + (size_t)b * A_ + a0;   // L1-resident (~1 KB per block)

    float acc = 0.0f;
    #pragma unroll 4
    for (int t = tid; t < total; t += APB) {
        const int la = t / C4;                 // magic-mul, cheap
        const float4 v = cp[t];                // regular load (m13: 6.29 TB/s path)
        float s = f_neg(clampp(v.x));
        s += f_neg(clampp(v.y));
        s += f_neg(clampp(v.z));
        s += f_neg(clampp(v.w));
        acc = fmaf(mb[la], s, acc);
    }

    #pragma unroll
    for (int off = 32; off > 0; off >>= 1) acc += __shfl_down(acc, off, 64);
    if ((tid & 63) == 0) s_red[tid >> 6] = acc;
    __syncthreads();
    if (tid == 0)
        PB_cls[b * GX + blockIdx.x] = s_red[0] + s_red[1] + s_red[2] + s_red[3];
}

// ---------------- Kernel C: finalize (one wave per image) --------------------
__global__ __launch_bounds__(512) void fin_k(
    const float* __restrict__ PA_reg,
    const float* __restrict__ PA_np,
    const float* __restrict__ PA_cor,
    const float* __restrict__ PB_cls,
    float* __restrict__ out)
{
    __shared__ float s_cm[8], s_rm[8];
    const int tid  = threadIdx.x;
    const int lane = tid & 63;
    const int b    = tid >> 6;      // 8 waves, one per image

    float c = 0.0f, r = 0.0f, n = 0.0f;
    for (int x = lane; x < GX; x += 64) {
        c += PB_cls[b * GX + x] + PA_cor[b * GX + x];
        r += PA_reg[b * GX + x];
        n += PA_np [b * GX + x];
    }
    #pragma unroll
    for (int off = 32; off > 0; off >>= 1) {
        c += __shfl_down(c, off, 64);
        r += __shfl_down(r, off, 64);
        n += __shfl_down(n, off, 64);
    }
    if (lane == 0) {
        s_cm[b] = c / fmaxf(n, 1.0f);
        s_rm[b] = (n > 0.0f) ? r / fmaxf(4.0f * n, 1.0f) : 0.0f;
    }
    __syncthreads();
    if (tid == 0) {
        float cm = 0.0f, rm = 0.0f;
        #pragma unroll
        for (int i = 0; i < B_; ++i) { cm += s_cm[i]; rm += s_rm[i]; }
        out[0] = cm / (float)B_;
        out[1] = rm / (float)B_;
    }
}

extern "C" void kernel_launch(void* const* d_in, const int* in_sizes, int n_in,
                              void* d_out, int out_size, void* d_ws, size_t ws_size,
                              hipStream_t stream) {
    const float* cls = (const float*)d_in[0];   // [B,A,C]
    const float* reg = (const float*)d_in[1];   // [B,A,4]
    const float* anc = (const float*)d_in[2];   // [1,A,4]
    const float* ann = (const float*)d_in[3];   // [B,M,5]
    float* out = (float*)d_out;

    float* wsf    = (float*)d_ws;
    float* mask   = wsf + WS_MASK;
    float* PA_reg = wsf + WS_PA_REG;
    float* PA_np  = wsf + WS_PA_NP;
    float* PA_cor = wsf + WS_PA_COR;
    float* PB_cls = wsf + WS_PB_CLS;

    dim3 grid(GX, B_);
    assign_k<<<grid, APB, 0, stream>>>(cls, reg, anc, ann, mask, PA_reg, PA_np, PA_cor);
    stream_k<<<grid, APB, 0, stream>>>(cls, mask, PB_cls);
    fin_k<<<1, 512, 0, stream>>>(PA_reg, PA_np, PA_cor, PB_cls, out);
}